// Round 11
// baseline (144262.000 us; speedup 1.0000x reference)
//
#include <hip/hip_runtime.h>

typedef __attribute__((ext_vector_type(8))) short short8v;
typedef __attribute__((ext_vector_type(4))) float f32x4;
typedef unsigned short u16;

#define MFMA_BF16(a,b,c) __builtin_amdgcn_mfma_f32_16x16x32_bf16((a),(b),(c),0,0,0)

static constexpr int Bb = 256, Tt = 512;
static constexpr int NBLK = 16, NTHR = 512;   // block = 16 batch rows, fully independent

static constexpr size_t MU_OFF  = (size_t)Bb * Tt * 2;
static constexpr size_t LV_OFF  = MU_OFF  + (size_t)Bb * Tt * 256;
static constexpr size_t MUP_OFF = LV_OFF  + (size_t)Bb * Tt * 256;
static constexpr size_t LVP_OFF = MUP_OFF + (size_t)Bb * Tt * 256;

// ---------------- packed weights (global, read-only, L2-resident) ----------------
__device__ u16  g_wp_enc[196608];
__device__ u16  g_wp_pp[131072];
__device__ u16  g_wp_hh[786432];
__device__ u16  g_wp_mulv[131072];
__device__ u16  g_wp_mplp[131072];
__device__ u16  g_wp_phiz[65536];
__device__ u16  g_wp_ih[786432];
__device__ u16  g_wp_dec[12288];
__device__ u16  g_wp_phix[16384];

__device__ __forceinline__ u16 f2bf(float f) {
  unsigned u = __builtin_bit_cast(unsigned, f);
  u += 0x7FFFu + ((u >> 16) & 1u);
  return (u16)(u >> 16);
}
__device__ __forceinline__ float bf2f(u16 v) {
  unsigned u = ((unsigned)v) << 16;
  return __builtin_bit_cast(float, u);
}

struct Args {
  const float *x, *eps;
  const float *b_phix, *b_enc, *b_mu, *b_lv, *b_pp, *b_mup, *b_lvp, *b_phiz, *b_dec, *b_ih, *b_hh;
  float *out;
};

// ---------------- weight pre-pack into MFMA B-fragment layout ----------------
__device__ __forceinline__ u16* sel_wp(int sel) {
  switch (sel) {
    case 0: return g_wp_enc;  case 1: return g_wp_pp;   case 2: return g_wp_hh;
    case 3: return g_wp_mulv; case 4: return g_wp_mplp; case 5: return g_wp_phiz;
    case 6: return g_wp_ih;   case 7: return g_wp_dec;  default: return g_wp_phix;
  }
}

__global__ void pack_w(const float* __restrict__ src, int KT, int Nsrc,
                       int sel, int nnStart, int nnCount, int colBase) {
  int gid = blockIdx.x * 256 + threadIdx.x;
  int total = nnCount * KT * 64;
  if (gid >= total) return;
  u16* dstBase = sel_wp(sel);
  int lane = gid & 63;
  int rem  = gid >> 6;
  int kk   = rem % KT;
  int nn   = nnStart + rem / KT;
  int col  = nn * 16 + (lane & 15) - colBase;
  int krow = kk * 32 + ((lane >> 4) << 3);
  bool ok = (col >= 0) && (col < Nsrc);
  u16* d = dstBase + ((size_t)(nn * KT + kk) * 64 + lane) * 8;
#pragma unroll
  for (int i = 0; i < 8; ++i)
    d[i] = ok ? f2bf(src[(size_t)(krow + i) * Nsrc + col]) : (u16)0;
}

// ---------------- fragment loads ----------------
__device__ __forceinline__ short8v loadB(const u16* wp, int KT, int nn, int kk, int lane) {
  return *(const short8v*)(wp + ((size_t)(nn * KT + kk) * 64 + lane) * 8);
}
// A-frag from LDS tile (M=16 rows): lane l -> row (l&15), k = kcol + 8*(l>>4) + i
__device__ __forceinline__ short8v loadA_lds(const u16* buf, int stride, int kcol, int lane) {
  return *(const short8v*)(buf + (lane & 15) * stride + kcol + ((lane >> 4) << 3));
}
__device__ __forceinline__ short8v cvt8(const float* s) {
  short8v r;
#pragma unroll
  for (int i = 0; i < 8; ++i) r[i] = (short)f2bf(s[i]);
  return r;
}

__device__ __forceinline__ float sigm_(float x) { return 1.f / (1.f + __expf(-x)); }
__device__ __forceinline__ float tanh_(float x) {
  x = fminf(fmaxf(x, -15.f), 15.f);
  float e = __expf(2.f * x);
  return (e - 1.f) / (e + 1.f);
}

// ---------------- per-row-group persistent kernel: ZERO inter-block communication ----------------
// LDS layout (bank-conflict-aware strides: 260 elems = 520B ≡ bank+2/row; 516 f.s. for hb):
//   hb   [16][516] bf16  hidden state (bf16 mirror; fp32 master in registers)
//   phx  [16][260] bf16  phi_x(t)
//   ebuf [16][260] bf16  encb (P2-P3) then phizb (P4-P5)   [disjoint lifetimes]
//   zpb  [16][260] bf16
//   muB  [16][260] bf16
//   lvB  [16][260] bf16
__global__ __launch_bounds__(NTHR) void vrnn_block(Args a) {
  extern __shared__ char smem[];
  u16* hb   = (u16*)smem;                 // 16512 B
  u16* phx  = (u16*)(smem + 16512);       //  8320 B
  u16* ebuf = (u16*)(smem + 24832);       //  8320 B
  u16* zpb  = (u16*)(smem + 33152);       //  8320 B
  u16* muB  = (u16*)(smem + 41472);       //  8320 B
  u16* lvB  = (u16*)(smem + 49792);       //  8320 B -> 58112 total

  const int tid = threadIdx.x, lane = tid & 63, w = tid >> 6;
  const int R = blockIdx.x * 16;          // batch-row base
  const int cl = lane & 15, rb = (lane >> 4) << 2;
  const int kh = (lane >> 4) << 3;        // lane's k-offset within a 32-wide K chunk

  // fp32 hidden slice in registers: hreg[f][r] = h[R+rb+r][w*64 + f*16 + cl]
  f32x4 hreg[4];
#pragma unroll
  for (int f = 0; f < 4; ++f) hreg[f] = (f32x4){0.f, 0.f, 0.f, 0.f};

  for (int i = tid; i < 16 * 516; i += NTHR) hb[i] = 0;
  __syncthreads();

  for (int t = 0; t < Tt; ++t) {
    // ---- P1: phi_x(t) -> phx ----
    {
      const float* xb = a.x + (size_t)(R + cl) * 32768 + (size_t)t * 64;
#pragma unroll
      for (int j2 = 0; j2 < 2; ++j2) {
        int j = w * 2 + j2;
        f32x4 acc = (f32x4){0.f, 0.f, 0.f, 0.f};
#pragma unroll
        for (int kk = 0; kk < 2; ++kk) {
          short8v a0 = cvt8(xb + kk * 32 + kh);
          short8v b = loadB(g_wp_phix, 2, j, kk, lane);
          acc = MFMA_BF16(a0, b, acc);
        }
        int col = j * 16 + cl;
        float bb = a.b_phix[col];
#pragma unroll
        for (int r = 0; r < 4; ++r)
          phx[(rb + r) * 260 + col] = f2bf(fmaxf(acc[r] + bb, 0.f));
      }
    }
    __syncthreads();

    // ---- P2: enc = relu([phx|h]@W_enc), zp = relu(h@W_pp) ----
#pragma unroll
    for (int j2 = 0; j2 < 2; ++j2) {
      int j = w * 2 + j2;
      int col = j * 16 + cl;
      f32x4 ae = (f32x4){0.f, 0.f, 0.f, 0.f};
      for (int kk = 0; kk < 24; ++kk) {
        short8v a0 = (kk < 8) ? loadA_lds(phx, 260, kk * 32, lane)
                              : loadA_lds(hb, 516, (kk - 8) * 32, lane);
        short8v b = loadB(g_wp_enc, 24, j, kk, lane);
        ae = MFMA_BF16(a0, b, ae);
      }
      float be = a.b_enc[col];
#pragma unroll
      for (int r = 0; r < 4; ++r)
        ebuf[(rb + r) * 260 + col] = f2bf(fmaxf(ae[r] + be, 0.f));

      f32x4 az = (f32x4){0.f, 0.f, 0.f, 0.f};
      for (int kk = 0; kk < 16; ++kk) {
        short8v a0 = loadA_lds(hb, 516, kk * 32, lane);
        short8v b = loadB(g_wp_pp, 16, j, kk, lane);
        az = MFMA_BF16(a0, b, az);
      }
      float bz = a.b_pp[col];
#pragma unroll
      for (int r = 0; r < 4; ++r)
        zpb[(rb + r) * 260 + col] = f2bf(fmaxf(az[r] + bz, 0.f));
    }
    __syncthreads();

    // ---- P3: [mu|lv] = enc@W_mulv, [mup|lvp] = zp@W_mplp ----
#pragma unroll
    for (int j4 = 0; j4 < 4; ++j4) {
      int j = w * 4 + j4;
      int col = j * 16 + cl;
      bool isMu = col < 256;
      int c = isMu ? col : col - 256;

      f32x4 am = (f32x4){0.f, 0.f, 0.f, 0.f};
      for (int kk = 0; kk < 8; ++kk) {
        short8v a0 = loadA_lds(ebuf, 260, kk * 32, lane);
        short8v b = loadB(g_wp_mulv, 8, j, kk, lane);
        am = MFMA_BF16(a0, b, am);
      }
      float bm = isMu ? a.b_mu[c] : a.b_lv[c];
#pragma unroll
      for (int r = 0; r < 4; ++r) {
        float v = am[r] + bm;
        (isMu ? muB : lvB)[(rb + r) * 260 + c] = f2bf(v);
        __builtin_nontemporal_store(v,
          &a.out[(isMu ? MU_OFF : LV_OFF) + ((size_t)(R + rb + r) * 512 + t) * 256 + c]);
      }

      f32x4 ap = (f32x4){0.f, 0.f, 0.f, 0.f};
      for (int kk = 0; kk < 8; ++kk) {
        short8v a0 = loadA_lds(zpb, 260, kk * 32, lane);
        short8v b = loadB(g_wp_mplp, 8, j, kk, lane);
        ap = MFMA_BF16(a0, b, ap);
      }
      float bp = isMu ? a.b_mup[c] : a.b_lvp[c];
#pragma unroll
      for (int r = 0; r < 4; ++r)
        __builtin_nontemporal_store(ap[r] + bp,
          &a.out[(isMu ? MUP_OFF : LVP_OFF) + ((size_t)(R + rb + r) * 512 + t) * 256 + c]);
    }
    __syncthreads();

    // ---- P4: phi_z = relu(z@W_phiz), z = mu + eps*exp(0.5 lv)  -> ebuf (phizb) ----
#pragma unroll
    for (int j2 = 0; j2 < 2; ++j2) {
      int j = w * 2 + j2;
      f32x4 acc = (f32x4){0.f, 0.f, 0.f, 0.f};
      for (int kk = 0; kk < 8; ++kk) {
        int kc = kk * 32 + kh;
        const u16* mp = muB + cl * 260 + kc;
        const u16* lp = lvB + cl * 260 + kc;
        const float* ep = a.eps + ((size_t)(R + cl) * 512 + t) * 256 + kc;
        short8v av;
#pragma unroll
        for (int i = 0; i < 8; ++i) {
          float e = __builtin_nontemporal_load(ep + i);
          av[i] = (short)f2bf(bf2f(mp[i]) + e * __expf(0.5f * bf2f(lp[i])));
        }
        short8v b = loadB(g_wp_phiz, 8, j, kk, lane);
        acc = MFMA_BF16(av, b, acc);
      }
      int col = j * 16 + cl;
      float bb = a.b_phiz[col];
#pragma unroll
      for (int r = 0; r < 4; ++r)
        ebuf[(rb + r) * 260 + col] = f2bf(fmaxf(acc[r] + bb, 0.f));
    }
    __syncthreads();

    // ---- P5a: gh = h@W_hh, += gi = [phx|phiz]@W_ih (registers); outdec on wave 0 ----
    f32x4 aRZ[2][4], aHN[4], aIN[4];
#pragma unroll
    for (int g = 0; g < 2; ++g)
#pragma unroll
      for (int f = 0; f < 4; ++f) aRZ[g][f] = (f32x4){0.f, 0.f, 0.f, 0.f};
#pragma unroll
    for (int f = 0; f < 4; ++f) { aHN[f] = (f32x4){0.f, 0.f, 0.f, 0.f}; aIN[f] = (f32x4){0.f, 0.f, 0.f, 0.f}; }

    for (int kk = 0; kk < 16; ++kk) {
      short8v a0 = loadA_lds(hb, 516, kk * 32, lane);
#pragma unroll
      for (int g = 0; g < 2; ++g)
#pragma unroll
        for (int f = 0; f < 4; ++f) {
          short8v b = loadB(g_wp_hh, 16, g * 32 + w * 4 + f, kk, lane);
          aRZ[g][f] = MFMA_BF16(a0, b, aRZ[g][f]);
        }
#pragma unroll
      for (int f = 0; f < 4; ++f) {
        short8v b = loadB(g_wp_hh, 16, 64 + w * 4 + f, kk, lane);
        aHN[f] = MFMA_BF16(a0, b, aHN[f]);
      }
    }
    for (int kk = 0; kk < 16; ++kk) {
      short8v a0 = (kk < 8) ? loadA_lds(phx, 260, kk * 32, lane)
                            : loadA_lds(ebuf, 260, (kk - 8) * 32, lane);
#pragma unroll
      for (int g = 0; g < 2; ++g)
#pragma unroll
        for (int f = 0; f < 4; ++f) {
          short8v b = loadB(g_wp_ih, 16, g * 32 + w * 4 + f, kk, lane);
          aRZ[g][f] = MFMA_BF16(a0, b, aRZ[g][f]);
        }
#pragma unroll
      for (int f = 0; f < 4; ++f) {
        short8v b = loadB(g_wp_ih, 16, 64 + w * 4 + f, kk, lane);
        aIN[f] = MFMA_BF16(a0, b, aIN[f]);
      }
    }
    if (w == 0) {  // outdec: relu([phiz|h]@W_dec + b_dec) -> out[:, t, 0:2]
      f32x4 ad = (f32x4){0.f, 0.f, 0.f, 0.f};
      for (int kk = 0; kk < 24; ++kk) {
        short8v a0 = (kk < 8) ? loadA_lds(ebuf, 260, kk * 32, lane)
                              : loadA_lds(hb, 516, (kk - 8) * 32, lane);
        short8v b = loadB(g_wp_dec, 24, 0, kk, lane);
        ad = MFMA_BF16(a0, b, ad);
      }
      if (cl < 2) {
#pragma unroll
        for (int r = 0; r < 4; ++r) {
          float v = fmaxf(ad[r] + a.b_dec[cl], 0.f);
          __builtin_nontemporal_store(v, &a.out[(size_t)(R + rb + r) * 1024 + (size_t)t * 2 + cl]);
        }
      }
    }
    __syncthreads();   // all reads of hb/phx/ebuf done before hb is overwritten

    // ---- P5b: GRU epilogue; h in registers, bf16 mirror to LDS ----
#pragma unroll
    for (int f = 0; f < 4; ++f) {
      int jcol = w * 64 + f * 16 + cl;
      float br  = a.b_ih[jcol] + a.b_hh[jcol];
      float bz  = a.b_ih[512 + jcol] + a.b_hh[512 + jcol];
      float bin = a.b_ih[1024 + jcol];
      float bhn = a.b_hh[1024 + jcol];
#pragma unroll
      for (int r = 0; r < 4; ++r) {
        float rg = sigm_(aRZ[0][f][r] + br);
        float zg = sigm_(aRZ[1][f][r] + bz);
        float ng = tanh_(aIN[f][r] + bin + rg * (aHN[f][r] + bhn));
        float hv = (1.f - zg) * ng + zg * hreg[f][r];
        hreg[f][r] = hv;
        hb[(rb + r) * 516 + jcol] = f2bf(hv);
      }
    }
    __syncthreads();
  }
}

// ---------------- host launch ----------------
extern "C" void kernel_launch(void* const* d_in, const int* in_sizes, int n_in,
                              void* d_out, int out_size, void* d_ws, size_t ws_size,
                              hipStream_t stream) {
  const float* x      = (const float*)d_in[0];
  const float* eps    = (const float*)d_in[1];
  const float* W_phix = (const float*)d_in[2];  const float* b_phix = (const float*)d_in[3];
  const float* W_enc  = (const float*)d_in[4];  const float* b_enc  = (const float*)d_in[5];
  const float* W_mu   = (const float*)d_in[6];  const float* b_mu   = (const float*)d_in[7];
  const float* W_lv   = (const float*)d_in[8];  const float* b_lv   = (const float*)d_in[9];
  const float* W_pp   = (const float*)d_in[10]; const float* b_pp   = (const float*)d_in[11];
  const float* W_mup  = (const float*)d_in[12]; const float* b_mup  = (const float*)d_in[13];
  const float* W_lvp  = (const float*)d_in[14]; const float* b_lvp  = (const float*)d_in[15];
  const float* W_phiz = (const float*)d_in[16]; const float* b_phiz = (const float*)d_in[17];
  const float* W_dec  = (const float*)d_in[18]; const float* b_dec  = (const float*)d_in[19];
  // setup_inputs order: W_ih, W_hh, b_ih, b_hh
  const float* W_ih   = (const float*)d_in[20];
  const float* W_hh   = (const float*)d_in[21];
  const float* b_ih   = (const float*)d_in[22];
  const float* b_hh   = (const float*)d_in[23];
  (void)d_ws; (void)ws_size; (void)in_sizes; (void)n_in; (void)out_size;

  auto packL = [&](const float* src, int KT, int Nsrc, int sel, int nnStart, int nnCount, int colBase) {
    int total = nnCount * KT * 64;
    pack_w<<<(total + 255) / 256, 256, 0, stream>>>(src, KT, Nsrc, sel, nnStart, nnCount, colBase);
  };
  packL(W_enc, 24, 256, 0, 0, 16, 0);
  packL(W_pp, 16, 256, 1, 0, 16, 0);
  packL(W_hh, 16, 1536, 2, 0, 96, 0);
  packL(W_mu, 8, 256, 3, 0, 16, 0);
  packL(W_lv, 8, 256, 3, 16, 16, 256);
  packL(W_mup, 8, 256, 4, 0, 16, 0);
  packL(W_lvp, 8, 256, 4, 16, 16, 256);
  packL(W_phiz, 8, 256, 5, 0, 16, 0);
  packL(W_ih, 16, 1536, 6, 0, 96, 0);
  packL(W_dec, 24, 2, 7, 0, 1, 0);
  packL(W_phix, 2, 256, 8, 0, 16, 0);

  Args a;
  a.x = x; a.eps = eps;
  a.b_phix = b_phix; a.b_enc = b_enc; a.b_mu = b_mu; a.b_lv = b_lv; a.b_pp = b_pp;
  a.b_mup = b_mup; a.b_lvp = b_lvp; a.b_phiz = b_phiz; a.b_dec = b_dec; a.b_ih = b_ih; a.b_hh = b_hh;
  a.out = (float*)d_out;

  vrnn_block<<<NBLK, NTHR, 58112, stream>>>(a);
}

// Round 12
// 72704.004 us; speedup vs baseline: 1.9842x; 1.9842x over previous
//
#include <hip/hip_runtime.h>

typedef __attribute__((ext_vector_type(8))) short short8v;
typedef __attribute__((ext_vector_type(4))) float f32x4;
typedef unsigned short u16;
typedef unsigned long long u64;

#define MFMA_BF16(a,b,c) __builtin_amdgcn_mfma_f32_16x16x32_bf16((a),(b),(c),0,0,0)

static constexpr int Bb = 256, Tt = 512;
static constexpr int NBLK = 64, NTHR = 256;
// XCD role map (bid&7 = XCD on MI355X round-robin dispatch):
//  x=0: enc->mulv->phiz chain, rows 32k   (weights: enc+mulv+phiz = 0.77 MB resident)
//  x=1: zp->mplp chain, rows 32k          (pp+mplp = 0.51 MB)
//  x=2..5: gru, col-groups {2(x-2),2(x-2)+1} (hh+ih col-slice = 0.77 MB/XCD)
//  x=6: phix(t+1), rows 32k               (32 KB)
//  x=7: outdec (ph2), rows 32k            (24 KB)

static constexpr size_t MU_OFF  = (size_t)Bb * Tt * 2;
static constexpr size_t LV_OFF  = MU_OFF  + (size_t)Bb * Tt * 256;
static constexpr size_t MUP_OFF = LV_OFF  + (size_t)Bb * Tt * 256;
static constexpr size_t LVP_OFF = MUP_OFF + (size_t)Bb * Tt * 256;

// ---------------- static device scratch ----------------
__device__ u16  g_wp_enc[196608];
__device__ u16  g_wp_pp[131072];
__device__ u16  g_wp_hh[786432];
__device__ u16  g_wp_mulv[131072];
__device__ u16  g_wp_mplp[131072];
__device__ u16  g_wp_phiz[65536];
__device__ u16  g_wp_ih[786432];
__device__ u16  g_wp_dec[12288];
__device__ u16  g_wp_phix[16384];
__device__ u16  g_hb[2][131072];    // bf16 hidden (cross-XCD, write-through/uncached)
__device__ u16  g_phx[2][65536];    // bf16 phi_x
__device__ u16  g_phizb[65536];     // bf16 phi_z
__device__ unsigned g_ctr;

__device__ __forceinline__ u16 f2bf(float f) {
  unsigned u = __builtin_bit_cast(unsigned, f);
  u += 0x7FFFu + ((u >> 16) & 1u);
  return (u16)(u >> 16);
}
__device__ __forceinline__ float bf2f(u16 v) {
  unsigned u = ((unsigned)v) << 16;
  return __builtin_bit_cast(float, u);
}

struct Args {
  const float *x, *eps;
  const float *b_phix, *b_enc, *b_mu, *b_lv, *b_pp, *b_mup, *b_lvp, *b_phiz, *b_dec, *b_ih, *b_hh;
  float *out;
};

// ---------------- uncached (coherence-point) access helpers — R10-validated ----------------
__device__ __forceinline__ void st16(u16* p, u16 v) {
  __hip_atomic_store(p, v, __ATOMIC_RELAXED, __HIP_MEMORY_SCOPE_AGENT);
}
__device__ __forceinline__ short8v loadA_coh(const u16* buf, int stride, int m0, int kcol, int lane) {
  const u16* p = buf + (size_t)(m0 + (lane & 15)) * stride + kcol + ((lane >> 4) << 3);
  u64 lo = __hip_atomic_load((u64*)(void*)p,       __ATOMIC_RELAXED, __HIP_MEMORY_SCOPE_AGENT);
  u64 hi = __hip_atomic_load((u64*)(void*)(p + 4), __ATOMIC_RELAXED, __HIP_MEMORY_SCOPE_AGENT);
  union { u64 q[2]; short8v v; } u;
  u.q[0] = lo; u.q[1] = hi;
  return u.v;
}

// ---------------- weight pre-pack (unchanged layout) ----------------
__device__ __forceinline__ u16* sel_wp(int sel) {
  switch (sel) {
    case 0: return g_wp_enc;  case 1: return g_wp_pp;   case 2: return g_wp_hh;
    case 3: return g_wp_mulv; case 4: return g_wp_mplp; case 5: return g_wp_phiz;
    case 6: return g_wp_ih;   case 7: return g_wp_dec;  default: return g_wp_phix;
  }
}

__global__ void pack_w(const float* __restrict__ src, int KT, int Nsrc,
                       int sel, int nnStart, int nnCount, int colBase) {
  int gid = blockIdx.x * 256 + threadIdx.x;
  int total = nnCount * KT * 64;
  if (gid >= total) return;
  u16* dstBase = sel_wp(sel);
  int lane = gid & 63;
  int rem  = gid >> 6;
  int kk   = rem % KT;
  int nn   = nnStart + rem / KT;
  int col  = nn * 16 + (lane & 15) - colBase;
  int krow = kk * 32 + ((lane >> 4) << 3);
  bool ok = (col >= 0) && (col < Nsrc);
  u16* d = dstBase + ((size_t)(nn * KT + kk) * 64 + lane) * 8;
#pragma unroll
  for (int i = 0; i < 8; ++i)
    d[i] = ok ? f2bf(src[(size_t)(krow + i) * Nsrc + col]) : (u16)0;
}

// ---------------- fragment loads (cached weights / LDS) ----------------
__device__ __forceinline__ short8v loadB(const u16* wp, int KT, int nn, int kk, int lane) {
  return *(const short8v*)(wp + ((size_t)(nn * KT + kk) * 64 + lane) * 8);
}
__device__ __forceinline__ short8v loadA_bf(const u16* buf, int stride, int m0, int kcol, int lane) {
  return *(const short8v*)(buf + (size_t)(m0 + (lane & 15)) * stride + kcol + ((lane >> 4) << 3));
}
__device__ __forceinline__ short8v cvt8(const float* s) {
  short8v r;
#pragma unroll
  for (int i = 0; i < 8; ++i) r[i] = (short)f2bf(s[i]);
  return r;
}

__device__ __forceinline__ float sigm_(float x) { return 1.f / (1.f + __expf(-x)); }
__device__ __forceinline__ float tanh_(float x) {
  x = fminf(fmaxf(x, -15.f), 15.f);
  float e = __expf(2.f * x);
  return (e - 1.f) / (e + 1.f);
}

// ---------------- grid barrier: counter only, NO fences (R10-validated) ----------------
__device__ __forceinline__ void gbar(unsigned& epoch) {
  __syncthreads();
  if (threadIdx.x == 0) {
    __hip_atomic_fetch_add(&g_ctr, 1u, __ATOMIC_RELAXED, __HIP_MEMORY_SCOPE_AGENT);
    unsigned target = (++epoch) * (unsigned)NBLK;
    long guard = 0;
    while (__hip_atomic_load(&g_ctr, __ATOMIC_RELAXED, __HIP_MEMORY_SCOPE_AGENT) < target) {
      __builtin_amdgcn_s_sleep(2);
      if (++guard > (1l << 24)) break;  // never hard-hang
    }
  }
  __syncthreads();
}

// ---------------- chain jobs (block-local LDS intermediates, 32 rows) ----------------

__device__ void chain_enc(const Args& a, int R, int w, int t, u16* encb, int lane) {
  const u16* phx = g_phx[t & 1];
  const u16* hb  = g_hb[t & 1];
  const int n0 = w * 64, nn0 = n0 >> 4;
  f32x4 acc[2][4];
#pragma unroll
  for (int m = 0; m < 2; ++m)
#pragma unroll
    for (int f = 0; f < 4; ++f) acc[m][f] = (f32x4){0.f, 0.f, 0.f, 0.f};
  for (int kk = 0; kk < 24; ++kk) {
    short8v a0, a1;
    if (kk < 8) { a0 = loadA_coh(phx, 256, R, kk * 32, lane); a1 = loadA_coh(phx, 256, R + 16, kk * 32, lane); }
    else        { a0 = loadA_coh(hb, 512, R, (kk - 8) * 32, lane); a1 = loadA_coh(hb, 512, R + 16, (kk - 8) * 32, lane); }
#pragma unroll
    for (int f = 0; f < 4; ++f) {
      short8v b = loadB(g_wp_enc, 24, nn0 + f, kk, lane);
      acc[0][f] = MFMA_BF16(a0, b, acc[0][f]);
      acc[1][f] = MFMA_BF16(a1, b, acc[1][f]);
    }
  }
  const int cl = lane & 15, rb = (lane >> 4) << 2;
#pragma unroll
  for (int m = 0; m < 2; ++m)
#pragma unroll
    for (int f = 0; f < 4; ++f) {
      int col = n0 + f * 16 + cl;
      float bb = a.b_enc[col];
#pragma unroll
      for (int r = 0; r < 4; ++r) {
        int rl = m * 16 + rb + r;
        encb[rl * 264 + col] = f2bf(fmaxf(acc[m][f][r] + bb, 0.f));
      }
    }
}

__device__ void chain_mulv_one(const Args& a, int R, int j, int t, const u16* encb,
                               u16* muB, u16* lvB, int lane) {
  const int n0 = j * 64, nn0 = n0 >> 4;
  f32x4 acc[2][4];
#pragma unroll
  for (int m = 0; m < 2; ++m)
#pragma unroll
    for (int f = 0; f < 4; ++f) acc[m][f] = (f32x4){0.f, 0.f, 0.f, 0.f};
  for (int kk = 0; kk < 8; ++kk) {
    short8v a0 = loadA_bf(encb, 264, 0, kk * 32, lane);
    short8v a1 = loadA_bf(encb, 264, 16, kk * 32, lane);
#pragma unroll
    for (int f = 0; f < 4; ++f) {
      short8v b = loadB(g_wp_mulv, 8, nn0 + f, kk, lane);
      acc[0][f] = MFMA_BF16(a0, b, acc[0][f]);
      acc[1][f] = MFMA_BF16(a1, b, acc[1][f]);
    }
  }
  const int cl = lane & 15, rb = (lane >> 4) << 2;
#pragma unroll
  for (int m = 0; m < 2; ++m)
#pragma unroll
    for (int f = 0; f < 4; ++f) {
      int col = n0 + f * 16 + cl;
      bool isMu = col < 256;
      int c = isMu ? col : col - 256;
      float bb = isMu ? a.b_mu[c] : a.b_lv[c];
#pragma unroll
      for (int r = 0; r < 4; ++r) {
        int rl = m * 16 + rb + r;
        float v = acc[m][f][r] + bb;
        (isMu ? muB : lvB)[rl * 264 + c] = f2bf(v);
        __builtin_nontemporal_store(v,
          &a.out[(isMu ? MU_OFF : LV_OFF) + ((size_t)(R + rl) * 512 + t) * 256 + c]);
      }
    }
}

__device__ void chain_phiz(const Args& a, int R, int w, int t, const u16* muB, const u16* lvB, int lane) {
  const int n0 = w * 64, nn0 = n0 >> 4;
  f32x4 acc[2][4];
#pragma unroll
  for (int m = 0; m < 2; ++m)
#pragma unroll
    for (int f = 0; f < 4; ++f) acc[m][f] = (f32x4){0.f, 0.f, 0.f, 0.f};
  for (int kk = 0; kk < 8; ++kk) {
    short8v av[2];
#pragma unroll
    for (int m = 0; m < 2; ++m) {
      int rl = m * 16 + (lane & 15);
      int kc = kk * 32 + ((lane >> 4) << 3);
      const u16* mp = muB + rl * 264 + kc;
      const u16* lp = lvB + rl * 264 + kc;
      const float* ep = a.eps + ((size_t)(R + rl) * 512 + t) * 256 + kc;
#pragma unroll
      for (int i = 0; i < 8; ++i) {
        float e = __builtin_nontemporal_load(ep + i);
        av[m][i] = (short)f2bf(bf2f(mp[i]) + e * __expf(0.5f * bf2f(lp[i])));
      }
    }
#pragma unroll
    for (int f = 0; f < 4; ++f) {
      short8v b = loadB(g_wp_phiz, 8, nn0 + f, kk, lane);
      acc[0][f] = MFMA_BF16(av[0], b, acc[0][f]);
      acc[1][f] = MFMA_BF16(av[1], b, acc[1][f]);
    }
  }
  const int cl = lane & 15, rb = (lane >> 4) << 2;
#pragma unroll
  for (int m = 0; m < 2; ++m)
#pragma unroll
    for (int f = 0; f < 4; ++f) {
      int col = n0 + f * 16 + cl;
      float bb = a.b_phiz[col];
#pragma unroll
      for (int r = 0; r < 4; ++r) {
        int row = R + m * 16 + rb + r;
        st16(&g_phizb[(size_t)row * 256 + col], f2bf(fmaxf(acc[m][f][r] + bb, 0.f)));
      }
    }
}

__device__ void chain_zp(const Args& a, int R, int w, int t, u16* zpb, int lane) {
  const u16* hb = g_hb[t & 1];
  const int n0 = w * 64, nn0 = n0 >> 4;
  f32x4 acc[2][4];
#pragma unroll
  for (int m = 0; m < 2; ++m)
#pragma unroll
    for (int f = 0; f < 4; ++f) acc[m][f] = (f32x4){0.f, 0.f, 0.f, 0.f};
  for (int kk = 0; kk < 16; ++kk) {
    short8v a0 = loadA_coh(hb, 512, R, kk * 32, lane);
    short8v a1 = loadA_coh(hb, 512, R + 16, kk * 32, lane);
#pragma unroll
    for (int f = 0; f < 4; ++f) {
      short8v b = loadB(g_wp_pp, 16, nn0 + f, kk, lane);
      acc[0][f] = MFMA_BF16(a0, b, acc[0][f]);
      acc[1][f] = MFMA_BF16(a1, b, acc[1][f]);
    }
  }
  const int cl = lane & 15, rb = (lane >> 4) << 2;
#pragma unroll
  for (int m = 0; m < 2; ++m)
#pragma unroll
    for (int f = 0; f < 4; ++f) {
      int col = n0 + f * 16 + cl;
      float bb = a.b_pp[col];
#pragma unroll
      for (int r = 0; r < 4; ++r) {
        int rl = m * 16 + rb + r;
        zpb[rl * 264 + col] = f2bf(fmaxf(acc[m][f][r] + bb, 0.f));
      }
    }
}

__device__ void chain_mplp_one(const Args& a, int R, int j, int t, const u16* zpb, int lane) {
  const int n0 = j * 64, nn0 = n0 >> 4;
  f32x4 acc[2][4];
#pragma unroll
  for (int m = 0; m < 2; ++m)
#pragma unroll
    for (int f = 0; f < 4; ++f) acc[m][f] = (f32x4){0.f, 0.f, 0.f, 0.f};
  for (int kk = 0; kk < 8; ++kk) {
    short8v a0 = loadA_bf(zpb, 264, 0, kk * 32, lane);
    short8v a1 = loadA_bf(zpb, 264, 16, kk * 32, lane);
#pragma unroll
    for (int f = 0; f < 4; ++f) {
      short8v b = loadB(g_wp_mplp, 8, nn0 + f, kk, lane);
      acc[0][f] = MFMA_BF16(a0, b, acc[0][f]);
      acc[1][f] = MFMA_BF16(a1, b, acc[1][f]);
    }
  }
  const int cl = lane & 15, rb = (lane >> 4) << 2;
#pragma unroll
  for (int m = 0; m < 2; ++m)
#pragma unroll
    for (int f = 0; f < 4; ++f) {
      int col = n0 + f * 16 + cl;
      bool isMu = col < 256;
      int c = isMu ? col : col - 256;
      float bb = isMu ? a.b_mup[c] : a.b_lvp[c];
#pragma unroll
      for (int r = 0; r < 4; ++r) {
        int rl = m * 16 + rb + r;
        __builtin_nontemporal_store(acc[m][f][r] + bb,
          &a.out[(isMu ? MUP_OFF : LVP_OFF) + ((size_t)(R + rl) * 512 + t) * 256 + c]);
      }
    }
}

// phi_x(tt): x (NT) -> g_phx[tt&1] (uncached st); j in [0,32)
__device__ void job_phix(const Args& a, int j, int tt, int lane) {
  u16* dst = g_phx[tt & 1];
  const int m0 = (j >> 2) * 32, n0 = (j & 3) * 64, nn0 = n0 >> 4;
  const float* xb = a.x + (size_t)tt * 64;
  f32x4 acc[2][4];
#pragma unroll
  for (int m = 0; m < 2; ++m)
#pragma unroll
    for (int f = 0; f < 4; ++f) acc[m][f] = (f32x4){0.f, 0.f, 0.f, 0.f};
  for (int kk = 0; kk < 2; ++kk) {
    int kc = kk * 32 + ((lane >> 4) << 3);
    short8v a0 = cvt8(xb + (size_t)(m0 + (lane & 15)) * 32768 + kc);
    short8v a1 = cvt8(xb + (size_t)(m0 + 16 + (lane & 15)) * 32768 + kc);
#pragma unroll
    for (int f = 0; f < 4; ++f) {
      short8v b = loadB(g_wp_phix, 2, nn0 + f, kk, lane);
      acc[0][f] = MFMA_BF16(a0, b, acc[0][f]);
      acc[1][f] = MFMA_BF16(a1, b, acc[1][f]);
    }
  }
  const int cl = lane & 15, rb = (lane >> 4) << 2;
#pragma unroll
  for (int m = 0; m < 2; ++m)
#pragma unroll
    for (int f = 0; f < 4; ++f) {
      int col = n0 + f * 16 + cl;
      float bb = a.b_phix[col];
#pragma unroll
      for (int r = 0; r < 4; ++r) {
        int row = m0 + m * 16 + rb + r;
        st16(&dst[(size_t)row * 256 + col], f2bf(fmaxf(acc[m][f][r] + bb, 0.f)));
      }
    }
}

// out = relu([phi_z | h] @ W_dec + b_dec); rows 32j, ph2
__device__ void job_outdec(const Args& a, int j, int t, int lane) {
  const u16* hb = g_hb[t & 1];
  const int m0 = j * 32;
  f32x4 acc[2];
  acc[0] = (f32x4){0.f, 0.f, 0.f, 0.f};
  acc[1] = (f32x4){0.f, 0.f, 0.f, 0.f};
  for (int kk = 0; kk < 24; ++kk) {
    short8v a0, a1;
    if (kk < 8) { a0 = loadA_coh(g_phizb, 256, m0, kk * 32, lane); a1 = loadA_coh(g_phizb, 256, m0 + 16, kk * 32, lane); }
    else        { a0 = loadA_coh(hb, 512, m0, (kk - 8) * 32, lane); a1 = loadA_coh(hb, 512, m0 + 16, (kk - 8) * 32, lane); }
    short8v b = loadB(g_wp_dec, 24, 0, kk, lane);
    acc[0] = MFMA_BF16(a0, b, acc[0]);
    acc[1] = MFMA_BF16(a1, b, acc[1]);
  }
  const int cl = lane & 15, rb = (lane >> 4) << 2;
  if (cl < 2) {
#pragma unroll
    for (int m = 0; m < 2; ++m)
#pragma unroll
      for (int r = 0; r < 4; ++r) {
        int row = m0 + m * 16 + rb + r;
        float v = fmaxf(acc[m][r] + a.b_dec[cl], 0.f);
        __builtin_nontemporal_store(v, &a.out[(size_t)row * 1024 + (size_t)t * 2 + cl]);
      }
  }
}

// ---------------- persistent kernel (XCD-role-pinned) ----------------
__global__ __launch_bounds__(NTHR) void vrnn_main(Args a) {
  extern __shared__ char smem[];
  const int tid = threadIdx.x, lane = tid & 63, w = tid >> 6, bid = blockIdx.x;
  const int x = bid & 7;      // XCD (round-robin dispatch heuristic)
  const int k = bid >> 3;     // index within role, 0..7
  unsigned epoch = 0;

  u16* encb = (u16*)smem;            // [32][264]
  u16* muB  = (u16*)(smem + 16896);
  u16* lvB  = (u16*)(smem + 33792);
  u16* zpb  = (u16*)smem;

  const bool isGru = (x >= 2 && x <= 5);
  int gng = 0, gm0 = 0;
  if (isGru) { gng = 2 * (x - 2) + (w >> 1); gm0 = 32 * k + 16 * (w & 1); }

  // h slice in registers (fp32) for gru waves: hreg[f][r] = h[gm0+rb+r][gng*64+f*16+cl]
  f32x4 hreg[4];
#pragma unroll
  for (int f = 0; f < 4; ++f) hreg[f] = (f32x4){0.f, 0.f, 0.f, 0.f};
  f32x4 arz[2][4], ahn[4];   // gh accumulators, live across ph1->ph2 barrier

  // prologue: zero hb[0] (uncached), phi_x(0)
  for (int g = bid * NTHR + tid; g < 65536; g += NBLK * NTHR)
    __hip_atomic_store((unsigned*)g_hb[0] + g, 0u, __ATOMIC_RELAXED, __HIP_MEMORY_SCOPE_AGENT);
  if (x == 6) job_phix(a, k * 4 + w, 0, lane);
  gbar(epoch);

  for (int t = 0; t < Tt; ++t) {
    // ---------------- phase 1 ----------------
    if (x == 0) {
      int R = k * 32;
      chain_enc(a, R, w, t, encb, lane);
      __syncthreads();
      chain_mulv_one(a, R, w, t, encb, muB, lvB, lane);
      chain_mulv_one(a, R, w + 4, t, encb, muB, lvB, lane);
      __syncthreads();
      chain_phiz(a, R, w, t, muB, lvB, lane);
    } else if (x == 1) {
      int R = k * 32;
      chain_zp(a, R, w, t, zpb, lane);
      __syncthreads();
      chain_mplp_one(a, R, w, t, zpb, lane);
      chain_mplp_one(a, R, w + 4, t, zpb, lane);
    } else if (isGru) {
#pragma unroll
      for (int g = 0; g < 2; ++g)
#pragma unroll
        for (int f = 0; f < 4; ++f) arz[g][f] = (f32x4){0.f, 0.f, 0.f, 0.f};
#pragma unroll
      for (int f = 0; f < 4; ++f) ahn[f] = (f32x4){0.f, 0.f, 0.f, 0.f};
      const u16* hb = g_hb[t & 1];
      for (int kk = 0; kk < 16; ++kk) {
        short8v a0 = loadA_coh(hb, 512, gm0, kk * 32, lane);
#pragma unroll
        for (int g = 0; g < 2; ++g)
#pragma unroll
          for (int f = 0; f < 4; ++f) {
            short8v b = loadB(g_wp_hh, 16, g * 32 + gng * 4 + f, kk, lane);
            arz[g][f] = MFMA_BF16(a0, b, arz[g][f]);
          }
#pragma unroll
        for (int f = 0; f < 4; ++f) {
          short8v b = loadB(g_wp_hh, 16, 64 + gng * 4 + f, kk, lane);
          ahn[f] = MFMA_BF16(a0, b, ahn[f]);
        }
      }
    } else if (x == 6) {
      if (t + 1 < Tt) job_phix(a, k * 4 + w, t + 1, lane);
    }
    gbar(epoch);

    // ---------------- phase 2 ----------------
    if (isGru) {
      f32x4 ain[4];
#pragma unroll
      for (int f = 0; f < 4; ++f) ain[f] = (f32x4){0.f, 0.f, 0.f, 0.f};
      const u16* phx = g_phx[t & 1];
      for (int kk = 0; kk < 16; ++kk) {
        short8v a0 = (kk < 8) ? loadA_coh(phx, 256, gm0, kk * 32, lane)
                              : loadA_coh(g_phizb, 256, gm0, (kk - 8) * 32, lane);
#pragma unroll
        for (int g = 0; g < 2; ++g)
#pragma unroll
          for (int f = 0; f < 4; ++f) {
            short8v b = loadB(g_wp_ih, 16, g * 32 + gng * 4 + f, kk, lane);
            arz[g][f] = MFMA_BF16(a0, b, arz[g][f]);
          }
#pragma unroll
        for (int f = 0; f < 4; ++f) {
          short8v b = loadB(g_wp_ih, 16, 64 + gng * 4 + f, kk, lane);
          ain[f] = MFMA_BF16(a0, b, ain[f]);
        }
      }
      u16* hbn = g_hb[(t + 1) & 1];
      const int cl = lane & 15, rb = (lane >> 4) << 2;
#pragma unroll
      for (int f = 0; f < 4; ++f) {
        int jcol = gng * 64 + f * 16 + cl;
        float br  = a.b_ih[jcol] + a.b_hh[jcol];
        float bz  = a.b_ih[512 + jcol] + a.b_hh[512 + jcol];
        float bin = a.b_ih[1024 + jcol];
        float bhn = a.b_hh[1024 + jcol];
#pragma unroll
        for (int r = 0; r < 4; ++r) {
          int row = gm0 + rb + r;
          float rg = sigm_(arz[0][f][r] + br);
          float zg = sigm_(arz[1][f][r] + bz);
          float ng = tanh_(ain[f][r] + bin + rg * (ahn[f][r] + bhn));
          float hv = (1.f - zg) * ng + zg * hreg[f][r];
          hreg[f][r] = hv;
          st16(&hbn[(size_t)row * 512 + jcol], f2bf(hv));
        }
      }
    } else if (x == 7 && w == 0) {
      job_outdec(a, k, t, lane);
    }
    gbar(epoch);
  }
}

// ---------------- host launch ----------------
extern "C" void kernel_launch(void* const* d_in, const int* in_sizes, int n_in,
                              void* d_out, int out_size, void* d_ws, size_t ws_size,
                              hipStream_t stream) {
  const float* x      = (const float*)d_in[0];
  const float* eps    = (const float*)d_in[1];
  const float* W_phix = (const float*)d_in[2];  const float* b_phix = (const float*)d_in[3];
  const float* W_enc  = (const float*)d_in[4];  const float* b_enc  = (const float*)d_in[5];
  const float* W_mu   = (const float*)d_in[6];  const float* b_mu   = (const float*)d_in[7];
  const float* W_lv   = (const float*)d_in[8];  const float* b_lv   = (const float*)d_in[9];
  const float* W_pp   = (const float*)d_in[10]; const float* b_pp   = (const float*)d_in[11];
  const float* W_mup  = (const float*)d_in[12]; const float* b_mup  = (const float*)d_in[13];
  const float* W_lvp  = (const float*)d_in[14]; const float* b_lvp  = (const float*)d_in[15];
  const float* W_phiz = (const float*)d_in[16]; const float* b_phiz = (const float*)d_in[17];
  const float* W_dec  = (const float*)d_in[18]; const float* b_dec  = (const float*)d_in[19];
  // setup_inputs order: W_ih, W_hh, b_ih, b_hh
  const float* W_ih   = (const float*)d_in[20];
  const float* W_hh   = (const float*)d_in[21];
  const float* b_ih   = (const float*)d_in[22];
  const float* b_hh   = (const float*)d_in[23];
  (void)d_ws; (void)ws_size; (void)in_sizes; (void)n_in; (void)out_size;

  void* ctrAddr = nullptr;
  (void)hipGetSymbolAddress(&ctrAddr, HIP_SYMBOL(g_ctr));
  (void)hipMemsetAsync(ctrAddr, 0, sizeof(unsigned), stream);

  auto packL = [&](const float* src, int KT, int Nsrc, int sel, int nnStart, int nnCount, int colBase) {
    int total = nnCount * KT * 64;
    pack_w<<<(total + 255) / 256, 256, 0, stream>>>(src, KT, Nsrc, sel, nnStart, nnCount, colBase);
  };
  packL(W_enc, 24, 256, 0, 0, 16, 0);
  packL(W_pp, 16, 256, 1, 0, 16, 0);
  packL(W_hh, 16, 1536, 2, 0, 96, 0);
  packL(W_mu, 8, 256, 3, 0, 16, 0);
  packL(W_lv, 8, 256, 3, 16, 16, 256);
  packL(W_mup, 8, 256, 4, 0, 16, 0);
  packL(W_lvp, 8, 256, 4, 16, 16, 256);
  packL(W_phiz, 8, 256, 5, 0, 16, 0);
  packL(W_ih, 16, 1536, 6, 0, 96, 0);
  packL(W_dec, 24, 2, 7, 0, 1, 0);
  packL(W_phix, 2, 256, 8, 0, 16, 0);

  Args a;
  a.x = x; a.eps = eps;
  a.b_phix = b_phix; a.b_enc = b_enc; a.b_mu = b_mu; a.b_lv = b_lv; a.b_pp = b_pp;
  a.b_mup = b_mup; a.b_lvp = b_lvp; a.b_phiz = b_phiz; a.b_dec = b_dec; a.b_ih = b_ih; a.b_hh = b_hh;
  a.out = (float*)d_out;

  vrnn_main<<<NBLK, NTHR, 50688, stream>>>(a);
}

// Round 13
// 68700.647 us; speedup vs baseline: 2.0999x; 1.0583x over previous
//
#include <hip/hip_runtime.h>

typedef __attribute__((ext_vector_type(8))) short short8v;
typedef __attribute__((ext_vector_type(4))) float f32x4;
typedef unsigned short u16;
typedef unsigned long long u64;

#define MFMA_BF16(a,b,c) __builtin_amdgcn_mfma_f32_16x16x32_bf16((a),(b),(c),0,0,0)

static constexpr int Bb = 256, Tt = 512;
static constexpr int NBLK = 128, NTHR = 256;
// role map (x = bid&7 -> XCD on round-robin dispatch; k = bid>>3 in 0..15):
//  x=0: enc->mulv->phiz chain, 16 rows (k=0..15)
//  x=1: zp->mplp chain, 16 rows (k=0..15)
//  x=2..5: gru col-groups, 32 rows (k=0..7 active)
//  x=6: phix(t+1), 2 jobs (k=0..15)
//  x=7: outdec ph2, 32 rows (k=0..7 active)
// Correctness does NOT depend on placement (uncached state + barrier); only perf.

static constexpr size_t MU_OFF  = (size_t)Bb * Tt * 2;
static constexpr size_t LV_OFF  = MU_OFF  + (size_t)Bb * Tt * 256;
static constexpr size_t MUP_OFF = LV_OFF  + (size_t)Bb * Tt * 256;
static constexpr size_t LVP_OFF = MUP_OFF + (size_t)Bb * Tt * 256;

// ---------------- static device scratch ----------------
__device__ u16  g_wp_enc[196608];
__device__ u16  g_wp_pp[131072];
__device__ u16  g_wp_hh[786432];
__device__ u16  g_wp_mulv[131072];
__device__ u16  g_wp_mplp[131072];
__device__ u16  g_wp_phiz[65536];
__device__ u16  g_wp_ih[786432];
__device__ u16  g_wp_dec[12288];
__device__ u16  g_wp_phix[16384];
__device__ u16  g_hb[2][131072];    // bf16 hidden (cross-XCD, uncached)
__device__ u16  g_phx[2][65536];    // bf16 phi_x
__device__ u16  g_phizb[65536];     // bf16 phi_z
__device__ unsigned g_ctr;

__device__ __forceinline__ u16 f2bf(float f) {
  unsigned u = __builtin_bit_cast(unsigned, f);
  u += 0x7FFFu + ((u >> 16) & 1u);
  return (u16)(u >> 16);
}
__device__ __forceinline__ float bf2f(u16 v) {
  unsigned u = ((unsigned)v) << 16;
  return __builtin_bit_cast(float, u);
}

struct Args {
  const float *x, *eps;
  const float *b_phix, *b_enc, *b_mu, *b_lv, *b_pp, *b_mup, *b_lvp, *b_phiz, *b_dec, *b_ih, *b_hh;
  float *out;
};

// ---------------- uncached access (R10/R12-validated) ----------------
__device__ __forceinline__ void st16(u16* p, u16 v) {
  __hip_atomic_store(p, v, __ATOMIC_RELAXED, __HIP_MEMORY_SCOPE_AGENT);
}
// cooperative stage: uncached global [rows][2^colsLog2] (srcStride elems) -> LDS (dstStride elems)
__device__ __forceinline__ void stage_coh(const u16* src, int srcStride, int rows, int colsLog2,
                                          u16* dst, int dstStride, int tid) {
  int total = (rows << colsLog2) >> 3;
  int colsMask = (1 << colsLog2) - 1;
  for (int i = tid; i < total; i += NTHR) {
    int e = i << 3;
    int r = e >> colsLog2, c = e & colsMask;
    const u16* p = src + (size_t)r * srcStride + c;
    u64 lo = __hip_atomic_load((u64*)(void*)p,       __ATOMIC_RELAXED, __HIP_MEMORY_SCOPE_AGENT);
    u64 hi = __hip_atomic_load((u64*)(void*)(p + 4), __ATOMIC_RELAXED, __HIP_MEMORY_SCOPE_AGENT);
    u16* d = dst + r * dstStride + c;
    *(u64*)d = lo;
    *(u64*)(d + 4) = hi;
  }
}

// ---------------- weight pre-pack (unchanged layout) ----------------
__device__ __forceinline__ u16* sel_wp(int sel) {
  switch (sel) {
    case 0: return g_wp_enc;  case 1: return g_wp_pp;   case 2: return g_wp_hh;
    case 3: return g_wp_mulv; case 4: return g_wp_mplp; case 5: return g_wp_phiz;
    case 6: return g_wp_ih;   case 7: return g_wp_dec;  default: return g_wp_phix;
  }
}

__global__ void pack_w(const float* __restrict__ src, int KT, int Nsrc,
                       int sel, int nnStart, int nnCount, int colBase) {
  int gid = blockIdx.x * 256 + threadIdx.x;
  int total = nnCount * KT * 64;
  if (gid >= total) return;
  u16* dstBase = sel_wp(sel);
  int lane = gid & 63;
  int rem  = gid >> 6;
  int kk   = rem % KT;
  int nn   = nnStart + rem / KT;
  int col  = nn * 16 + (lane & 15) - colBase;
  int krow = kk * 32 + ((lane >> 4) << 3);
  bool ok = (col >= 0) && (col < Nsrc);
  u16* d = dstBase + ((size_t)(nn * KT + kk) * 64 + lane) * 8;
#pragma unroll
  for (int i = 0; i < 8; ++i)
    d[i] = ok ? f2bf(src[(size_t)(krow + i) * Nsrc + col]) : (u16)0;
}

// ---------------- fragment loads ----------------
__device__ __forceinline__ short8v loadB(const u16* wp, int KT, int nn, int kk, int lane) {
  return *(const short8v*)(wp + ((size_t)(nn * KT + kk) * 64 + lane) * 8);
}
// A-frag from LDS tile: row m0+(lane&15), k = kcol + 8*(lane>>4) + i
__device__ __forceinline__ short8v ldsA(const u16* buf, int stride, int m0, int kcol, int lane) {
  return *(const short8v*)(buf + (m0 + (lane & 15)) * stride + kcol + ((lane >> 4) << 3));
}
__device__ __forceinline__ short8v cvt8(const float* s) {
  short8v r;
#pragma unroll
  for (int i = 0; i < 8; ++i) r[i] = (short)f2bf(s[i]);
  return r;
}

__device__ __forceinline__ float sigm_(float x) { return 1.f / (1.f + __expf(-x)); }
__device__ __forceinline__ float tanh_(float x) {
  x = fminf(fmaxf(x, -15.f), 15.f);
  float e = __expf(2.f * x);
  return (e - 1.f) / (e + 1.f);
}

// ---------------- grid barrier: counter only, NO fences (R10/R12-validated) ----------------
__device__ __forceinline__ void gbar(unsigned& epoch) {
  __syncthreads();
  if (threadIdx.x == 0) {
    __hip_atomic_fetch_add(&g_ctr, 1u, __ATOMIC_RELAXED, __HIP_MEMORY_SCOPE_AGENT);
    unsigned target = (++epoch) * (unsigned)NBLK;
    long guard = 0;
    while (__hip_atomic_load(&g_ctr, __ATOMIC_RELAXED, __HIP_MEMORY_SCOPE_AGENT) < target) {
      __builtin_amdgcn_s_sleep(2);
      if (++guard > (1l << 24)) break;  // never hard-hang
    }
  }
  __syncthreads();
}

// phi_x(tt): x (cached) -> g_phx[tt&1] (uncached st); j in [0,32)
__device__ void job_phix(const Args& a, int j, int tt, int lane) {
  u16* dst = g_phx[tt & 1];
  const int m0 = (j >> 2) * 32, n0 = (j & 3) * 64, nn0 = n0 >> 4;
  const float* xb = a.x + (size_t)tt * 64;
  f32x4 acc[2][4];
#pragma unroll
  for (int m = 0; m < 2; ++m)
#pragma unroll
    for (int f = 0; f < 4; ++f) acc[m][f] = (f32x4){0.f, 0.f, 0.f, 0.f};
  for (int kk = 0; kk < 2; ++kk) {
    int kc = kk * 32 + ((lane >> 4) << 3);
    short8v a0 = cvt8(xb + (size_t)(m0 + (lane & 15)) * 32768 + kc);
    short8v a1 = cvt8(xb + (size_t)(m0 + 16 + (lane & 15)) * 32768 + kc);
#pragma unroll
    for (int f = 0; f < 4; ++f) {
      short8v b = loadB(g_wp_phix, 2, nn0 + f, kk, lane);
      acc[0][f] = MFMA_BF16(a0, b, acc[0][f]);
      acc[1][f] = MFMA_BF16(a1, b, acc[1][f]);
    }
  }
  const int cl = lane & 15, rb = (lane >> 4) << 2;
#pragma unroll
  for (int m = 0; m < 2; ++m)
#pragma unroll
    for (int f = 0; f < 4; ++f) {
      int col = n0 + f * 16 + cl;
      float bb = a.b_phix[col];
#pragma unroll
      for (int r = 0; r < 4; ++r) {
        int row = m0 + m * 16 + rb + r;
        st16(&dst[(size_t)row * 256 + col], f2bf(fmaxf(acc[m][f][r] + bb, 0.f)));
      }
    }
}

// ---------------- persistent kernel ----------------
__global__ __launch_bounds__(NTHR) void vrnn_main(Args a) {
  extern __shared__ char smem[];
  u16* S = (u16*)smem;
  const int tid = threadIdx.x, lane = tid & 63, w = tid >> 6, bid = blockIdx.x;
  const int x = bid & 7, k = bid >> 3;
  const int cl = lane & 15, rb = (lane >> 4) << 2, kh = (lane >> 4) << 3;
  unsigned epoch = 0;

  const bool isGru = (x >= 2 && x <= 5) && (k < 8);
  int gng = 0, gm0 = 0, gl0 = 0;
  if (x >= 2 && x <= 5) { gng = 2 * (x - 2) + (w >> 1); gm0 = 32 * k + 16 * (w & 1); gl0 = 16 * (w & 1); }

  f32x4 hreg[4];
#pragma unroll
  for (int f = 0; f < 4; ++f) hreg[f] = (f32x4){0.f, 0.f, 0.f, 0.f};
  f32x4 arz[2][4], ahn[4];   // gh accumulators, live across ph1->ph2 barrier

  // prologue
  for (int g = bid * NTHR + tid; g < 65536; g += NBLK * NTHR)
    __hip_atomic_store((unsigned*)g_hb[0] + g, 0u, __ATOMIC_RELAXED, __HIP_MEMORY_SCOPE_AGENT);
  if (x == 6 && w < 2) job_phix(a, k * 2 + w, 0, lane);
  gbar(epoch);

  for (int t = 0; t < Tt; ++t) {
    // ================= phase 1 =================
    if (x == 0) {
      // enc -> mulv -> phiz chain, rows R..R+16
      const int R = 16 * k;
      u16* phxS = S;                    // [16][264]
      u16* hbS  = S + 16 * 264;         // [16][520]
      u16* encb = hbS + 16 * 520;       // [16][264]
      stage_coh(g_phx[t & 1] + (size_t)R * 256, 256, 16, 8, phxS, 264, tid);
      stage_coh(g_hb[t & 1] + (size_t)R * 512, 512, 16, 9, hbS, 520, tid);
      __syncthreads();
      {  // enc: wave w -> cols w*64
        f32x4 acc[4];
#pragma unroll
        for (int f = 0; f < 4; ++f) acc[f] = (f32x4){0.f, 0.f, 0.f, 0.f};
        for (int kk = 0; kk < 24; ++kk) {
          short8v a0 = (kk < 8) ? ldsA(phxS, 264, 0, kk * 32, lane)
                                : ldsA(hbS, 520, 0, (kk - 8) * 32, lane);
#pragma unroll
          for (int f = 0; f < 4; ++f) {
            short8v b = loadB(g_wp_enc, 24, w * 4 + f, kk, lane);
            acc[f] = MFMA_BF16(a0, b, acc[f]);
          }
        }
#pragma unroll
        for (int f = 0; f < 4; ++f) {
          int col = w * 64 + f * 16 + cl;
          float bb = a.b_enc[col];
#pragma unroll
          for (int r = 0; r < 4; ++r)
            encb[(rb + r) * 264 + col] = f2bf(fmaxf(acc[f][r] + bb, 0.f));
        }
      }
      __syncthreads();
      u16* muB = phxS;  // phx dead
      u16* lvB = hbS;   // hb dead (use stride 264 layout)
      {  // mulv: wave w -> cols w*128 of 512
        f32x4 am[8];
#pragma unroll
        for (int f = 0; f < 8; ++f) am[f] = (f32x4){0.f, 0.f, 0.f, 0.f};
        for (int kk = 0; kk < 8; ++kk) {
          short8v a0 = ldsA(encb, 264, 0, kk * 32, lane);
#pragma unroll
          for (int f = 0; f < 8; ++f) {
            short8v b = loadB(g_wp_mulv, 8, w * 8 + f, kk, lane);
            am[f] = MFMA_BF16(a0, b, am[f]);
          }
        }
        __syncthreads();  // everyone done reading phxS/hbS before muB/lvB writes
#pragma unroll
        for (int f = 0; f < 8; ++f) {
          int col = w * 128 + f * 16 + cl;
          bool isMu = col < 256;
          int c = isMu ? col : col - 256;
          float bb = isMu ? a.b_mu[c] : a.b_lv[c];
#pragma unroll
          for (int r = 0; r < 4; ++r) {
            float v = am[f][r] + bb;
            (isMu ? muB : lvB)[(rb + r) * 264 + c] = f2bf(v);
            __builtin_nontemporal_store(v,
              &a.out[(isMu ? MU_OFF : LV_OFF) + ((size_t)(R + rb + r) * 512 + t) * 256 + c]);
          }
        }
      }
      __syncthreads();
      {  // phiz: wave w -> cols w*64; z built from muB/lvB + eps
        f32x4 ap[4];
#pragma unroll
        for (int f = 0; f < 4; ++f) ap[f] = (f32x4){0.f, 0.f, 0.f, 0.f};
        for (int kk = 0; kk < 8; ++kk) {
          int kc = kk * 32 + kh;
          const u16* mp = muB + cl * 264 + kc;
          const u16* lp = lvB + cl * 264 + kc;
          const float* ep = a.eps + ((size_t)(R + cl) * 512 + t) * 256 + kc;
          short8v av;
#pragma unroll
          for (int i = 0; i < 8; ++i) {
            float e = __builtin_nontemporal_load(ep + i);
            av[i] = (short)f2bf(bf2f(mp[i]) + e * __expf(0.5f * bf2f(lp[i])));
          }
#pragma unroll
          for (int f = 0; f < 4; ++f) {
            short8v b = loadB(g_wp_phiz, 8, w * 4 + f, kk, lane);
            ap[f] = MFMA_BF16(av, b, ap[f]);
          }
        }
#pragma unroll
        for (int f = 0; f < 4; ++f) {
          int col = w * 64 + f * 16 + cl;
          float bb = a.b_phiz[col];
#pragma unroll
          for (int r = 0; r < 4; ++r)
            st16(&g_phizb[(size_t)(R + rb + r) * 256 + col], f2bf(fmaxf(ap[f][r] + bb, 0.f)));
        }
      }
    } else if (x == 1) {
      // zp -> mplp chain, rows R..R+16
      const int R = 16 * k;
      u16* hbS = S;                 // [16][520]
      u16* zpb = S + 16 * 520;      // [16][264]
      stage_coh(g_hb[t & 1] + (size_t)R * 512, 512, 16, 9, hbS, 520, tid);
      __syncthreads();
      {  // zp
        f32x4 acc[4];
#pragma unroll
        for (int f = 0; f < 4; ++f) acc[f] = (f32x4){0.f, 0.f, 0.f, 0.f};
        for (int kk = 0; kk < 16; ++kk) {
          short8v a0 = ldsA(hbS, 520, 0, kk * 32, lane);
#pragma unroll
          for (int f = 0; f < 4; ++f) {
            short8v b = loadB(g_wp_pp, 16, w * 4 + f, kk, lane);
            acc[f] = MFMA_BF16(a0, b, acc[f]);
          }
        }
#pragma unroll
        for (int f = 0; f < 4; ++f) {
          int col = w * 64 + f * 16 + cl;
          float bb = a.b_pp[col];
#pragma unroll
          for (int r = 0; r < 4; ++r)
            zpb[(rb + r) * 264 + col] = f2bf(fmaxf(acc[f][r] + bb, 0.f));
        }
      }
      __syncthreads();
      {  // mplp
        f32x4 ap[8];
#pragma unroll
        for (int f = 0; f < 8; ++f) ap[f] = (f32x4){0.f, 0.f, 0.f, 0.f};
        for (int kk = 0; kk < 8; ++kk) {
          short8v a0 = ldsA(zpb, 264, 0, kk * 32, lane);
#pragma unroll
          for (int f = 0; f < 8; ++f) {
            short8v b = loadB(g_wp_mplp, 8, w * 8 + f, kk, lane);
            ap[f] = MFMA_BF16(a0, b, ap[f]);
          }
        }
#pragma unroll
        for (int f = 0; f < 8; ++f) {
          int col = w * 128 + f * 16 + cl;
          bool isMu = col < 256;
          int c = isMu ? col : col - 256;
          float bb = isMu ? a.b_mup[c] : a.b_lvp[c];
#pragma unroll
          for (int r = 0; r < 4; ++r)
            __builtin_nontemporal_store(ap[f][r] + bb,
              &a.out[(isMu ? MUP_OFF : LVP_OFF) + ((size_t)(R + rb + r) * 512 + t) * 256 + c]);
        }
      }
    } else if (isGru) {
      // gh = h@W_hh from LDS-staged hb
      u16* hbS = S;  // [32][520]
      stage_coh(g_hb[t & 1] + (size_t)(32 * k) * 512, 512, 32, 9, hbS, 520, tid);
      __syncthreads();
#pragma unroll
      for (int g = 0; g < 2; ++g)
#pragma unroll
        for (int f = 0; f < 4; ++f) arz[g][f] = (f32x4){0.f, 0.f, 0.f, 0.f};
#pragma unroll
      for (int f = 0; f < 4; ++f) ahn[f] = (f32x4){0.f, 0.f, 0.f, 0.f};
      for (int kk = 0; kk < 16; ++kk) {
        short8v a0 = ldsA(hbS, 520, gl0, kk * 32, lane);
#pragma unroll
        for (int g = 0; g < 2; ++g)
#pragma unroll
          for (int f = 0; f < 4; ++f) {
            short8v b = loadB(g_wp_hh, 16, g * 32 + gng * 4 + f, kk, lane);
            arz[g][f] = MFMA_BF16(a0, b, arz[g][f]);
          }
#pragma unroll
        for (int f = 0; f < 4; ++f) {
          short8v b = loadB(g_wp_hh, 16, 64 + gng * 4 + f, kk, lane);
          ahn[f] = MFMA_BF16(a0, b, ahn[f]);
        }
      }
    } else if (x == 6) {
      if (w < 2 && t + 1 < Tt) job_phix(a, k * 2 + w, t + 1, lane);
    }
    gbar(epoch);

    // ================= phase 2 =================
    if (isGru) {
      u16* phxS = S;                // [32][264]
      u16* pzS  = S + 32 * 264;     // [32][264]
      stage_coh(g_phx[t & 1] + (size_t)(32 * k) * 256, 256, 32, 8, phxS, 264, tid);
      stage_coh(g_phizb + (size_t)(32 * k) * 256, 256, 32, 8, pzS, 264, tid);
      __syncthreads();
      f32x4 ain[4];
#pragma unroll
      for (int f = 0; f < 4; ++f) ain[f] = (f32x4){0.f, 0.f, 0.f, 0.f};
      for (int kk = 0; kk < 16; ++kk) {
        short8v a0 = (kk < 8) ? ldsA(phxS, 264, gl0, kk * 32, lane)
                              : ldsA(pzS, 264, gl0, (kk - 8) * 32, lane);
#pragma unroll
        for (int g = 0; g < 2; ++g)
#pragma unroll
          for (int f = 0; f < 4; ++f) {
            short8v b = loadB(g_wp_ih, 16, g * 32 + gng * 4 + f, kk, lane);
            arz[g][f] = MFMA_BF16(a0, b, arz[g][f]);
          }
#pragma unroll
        for (int f = 0; f < 4; ++f) {
          short8v b = loadB(g_wp_ih, 16, 64 + gng * 4 + f, kk, lane);
          ain[f] = MFMA_BF16(a0, b, ain[f]);
        }
      }
      // GRU epilogue; h in registers, bf16 written uncached
      u16* hbn = g_hb[(t + 1) & 1];
#pragma unroll
      for (int f = 0; f < 4; ++f) {
        int jcol = gng * 64 + f * 16 + cl;
        float br  = a.b_ih[jcol] + a.b_hh[jcol];
        float bz  = a.b_ih[512 + jcol] + a.b_hh[512 + jcol];
        float bin = a.b_ih[1024 + jcol];
        float bhn = a.b_hh[1024 + jcol];
#pragma unroll
        for (int r = 0; r < 4; ++r) {
          int row = gm0 + rb + r;
          float rg = sigm_(arz[0][f][r] + br);
          float zg = sigm_(arz[1][f][r] + bz);
          float ng = tanh_(ain[f][r] + bin + rg * (ahn[f][r] + bhn));
          float hv = (1.f - zg) * ng + zg * hreg[f][r];
          hreg[f][r] = hv;
          st16(&hbn[(size_t)row * 512 + jcol], f2bf(hv));
        }
      }
    } else if (x == 7 && k < 8) {
      // outdec: rows 32k, staged phizb + hb
      u16* pzS = S;                 // [32][264]
      u16* hbS = S + 32 * 264;      // [32][520]
      stage_coh(g_phizb + (size_t)(32 * k) * 256, 256, 32, 8, pzS, 264, tid);
      stage_coh(g_hb[t & 1] + (size_t)(32 * k) * 512, 512, 32, 9, hbS, 520, tid);
      __syncthreads();
      if (w < 2) {
        f32x4 ad = (f32x4){0.f, 0.f, 0.f, 0.f};
        for (int kk = 0; kk < 24; ++kk) {
          short8v a0 = (kk < 8) ? ldsA(pzS, 264, 16 * w, kk * 32, lane)
                                : ldsA(hbS, 520, 16 * w, (kk - 8) * 32, lane);
          short8v b = loadB(g_wp_dec, 24, 0, kk, lane);
          ad = MFMA_BF16(a0, b, ad);
        }
        if (cl < 2) {
#pragma unroll
          for (int r = 0; r < 4; ++r) {
            int row = 32 * k + 16 * w + rb + r;
            float v = fmaxf(ad[r] + a.b_dec[cl], 0.f);
            __builtin_nontemporal_store(v, &a.out[(size_t)row * 1024 + (size_t)t * 2 + cl]);
          }
        }
      }
    }
    gbar(epoch);
  }
}

// ---------------- host launch ----------------
extern "C" void kernel_launch(void* const* d_in, const int* in_sizes, int n_in,
                              void* d_out, int out_size, void* d_ws, size_t ws_size,
                              hipStream_t stream) {
  const float* x      = (const float*)d_in[0];
  const float* eps    = (const float*)d_in[1];
  const float* W_phix = (const float*)d_in[2];  const float* b_phix = (const float*)d_in[3];
  const float* W_enc  = (const float*)d_in[4];  const float* b_enc  = (const float*)d_in[5];
  const float* W_mu   = (const float*)d_in[6];  const float* b_mu   = (const float*)d_in[7];
  const float* W_lv   = (const float*)d_in[8];  const float* b_lv   = (const float*)d_in[9];
  const float* W_pp   = (const float*)d_in[10]; const float* b_pp   = (const float*)d_in[11];
  const float* W_mup  = (const float*)d_in[12]; const float* b_mup  = (const float*)d_in[13];
  const float* W_lvp  = (const float*)d_in[14]; const float* b_lvp  = (const float*)d_in[15];
  const float* W_phiz = (const float*)d_in[16]; const float* b_phiz = (const float*)d_in[17];
  const float* W_dec  = (const float*)d_in[18]; const float* b_dec  = (const float*)d_in[19];
  // setup_inputs order: W_ih, W_hh, b_ih, b_hh
  const float* W_ih   = (const float*)d_in[20];
  const float* W_hh   = (const float*)d_in[21];
  const float* b_ih   = (const float*)d_in[22];
  const float* b_hh   = (const float*)d_in[23];
  (void)d_ws; (void)ws_size; (void)in_sizes; (void)n_in; (void)out_size;

  void* ctrAddr = nullptr;
  (void)hipGetSymbolAddress(&ctrAddr, HIP_SYMBOL(g_ctr));
  (void)hipMemsetAsync(ctrAddr, 0, sizeof(unsigned), stream);

  auto packL = [&](const float* src, int KT, int Nsrc, int sel, int nnStart, int nnCount, int colBase) {
    int total = nnCount * KT * 64;
    pack_w<<<(total + 255) / 256, 256, 0, stream>>>(src, KT, Nsrc, sel, nnStart, nnCount, colBase);
  };
  packL(W_enc, 24, 256, 0, 0, 16, 0);
  packL(W_pp, 16, 256, 1, 0, 16, 0);
  packL(W_hh, 16, 1536, 2, 0, 96, 0);
  packL(W_mu, 8, 256, 3, 0, 16, 0);
  packL(W_lv, 8, 256, 3, 16, 16, 256);
  packL(W_mup, 8, 256, 4, 0, 16, 0);
  packL(W_lvp, 8, 256, 4, 16, 16, 256);
  packL(W_phiz, 8, 256, 5, 0, 16, 0);
  packL(W_ih, 16, 1536, 6, 0, 96, 0);
  packL(W_dec, 24, 2, 7, 0, 1, 0);
  packL(W_phix, 2, 256, 8, 0, 16, 0);

  Args a;
  a.x = x; a.eps = eps;
  a.b_phix = b_phix; a.b_enc = b_enc; a.b_mu = b_mu; a.b_lv = b_lv; a.b_pp = b_pp;
  a.b_mup = b_mup; a.b_lvp = b_lvp; a.b_phiz = b_phiz; a.b_dec = b_dec; a.b_ih = b_ih; a.b_hh = b_hh;
  a.out = (float*)d_out;

  vrnn_main<<<NBLK, NTHR, 50432, stream>>>(a);
}